// Round 1
// baseline (1824.792 us; speedup 1.0000x reference)
//
#include <hip/hip_runtime.h>
#include <hip/hip_bf16.h>
#include <math.h>

// ---------------- problem constants ----------------
#define TPB   512        // 2 planes x 256 positions
#define NPOS  256        // time positions per block (incl. 64 halo)
#define HALO  64
#define TUSE  192        // useful time samples per tile
#define PUSE  48         // useful downsampled positions per tile (TUSE/4)
#define LSEQ  90000
#define DL    22500
#define NTILES 469       // ceil(22500/48)

// ws float layout: [0,512) oacc ; then transposed weights
#define WS_WFT 512
#define WS_WGT (512+12288)
#define WS_WST (512+24576)
#define WS_WRT (512+30720)
// total = 512 + 36864 floats = 149,504 bytes (<< ws_size)

__device__ __forceinline__ float fast_tanh(float x) {
    x = fminf(fmaxf(x, -30.f), 30.f);
    float t = exp2f(x * 2.8853901817f);          // e^(2x)
    return (t - 1.f) * __builtin_amdgcn_rcpf(t + 1.f);
}
__device__ __forceinline__ float fast_sigmoid(float x) {
    x = fminf(fmaxf(x, -30.f), 30.f);
    float e = exp2f(-x * 1.4426950408f);         // e^(-x)
    return __builtin_amdgcn_rcpf(1.f + e);
}

// Transpose weights for wave-uniform (scalar) access + zero the o-accumulator.
__global__ void prep_kernel(const float* __restrict__ Wf, const float* __restrict__ Wg,
                            const float* __restrict__ Ws, const float* __restrict__ Wr,
                            float* __restrict__ ws) {
    int idx = blockIdx.x * 256 + threadIdx.x;    // grid 48*256 = 12288
    if (idx < 512) ws[idx] = 0.f;
    if (idx < 12288) {
        // Wf flat: ((i*32+co)*32+c)*2+tap  ->  WfT: i*2048 + c*64 + tap*32 + co
        int tap = idx & 1, c = (idx >> 1) & 31, co = (idx >> 6) & 31, i = idx >> 11;
        int dst = i * 2048 + c * 64 + tap * 32 + co;
        ws[WS_WFT + dst] = Wf[idx];
        ws[WS_WGT + dst] = Wg[idx];
    }
    if (idx < 6144) {
        // Ws flat: (i*32+co)*32+c  ->  WsT: i*1024 + c*32 + co
        int c = idx & 31, co = (idx >> 5) & 31, i = idx >> 10;
        int dst = i * 1024 + c * 32 + co;
        ws[WS_WST + dst] = Ws[idx];
        ws[WS_WRT + dst] = Wr[idx];
    }
}

__global__ __launch_bounds__(TPB, 4) void wavenet_kernel(
    const float* __restrict__ x,
    const float* __restrict__ w0, const float* __restrict__ b0,
    const float* __restrict__ bf, const float* __restrict__ bg,
    const float* __restrict__ bs, const float* __restrict__ br,
    const float* __restrict__ wd, const float* __restrict__ bd,
    const float* __restrict__ fcW,
    const float* __restrict__ wT,     // ws + 512 (transposed weights, read-only)
    float* __restrict__ oacc)         // ws[0..512) fp32 accumulators
{
    __shared__ __align__(16) float hbuf[32][NPOS];   // h (then skip)
    __shared__ __align__(16) float obuf[32][NPOS];   // gated out (then ybuf)

    const int tid  = threadIdx.x;
    const int bidx = blockIdx.x;
    const int b    = bidx & 7;         // batch fastest -> fcW slice L3 reuse
    const int tile = bidx >> 3;
    const int p0   = tile * PUSE;
    const int t0   = p0 * 4;
    const int plane = (tid >= NPOS) ? 1 : 0;         // wave-uniform in fact
    const int pidx  = tid & (NPOS - 1);
    const int plu   = __builtin_amdgcn_readfirstlane(plane);  // force SGPR
    const int pos   = t0 - HALO + pidx;
    const bool valid = (pos >= 0);     // pos<0 must present h==0 (left pad)

    // ---------------- h0 = causal conv K=3 ----------------
    float xv0 = 0.f, xv1 = 0.f, xv2 = 0.f;
    {
        int t = pos - 2; if (t >= 0 && t < LSEQ) xv0 = x[b * LSEQ + t];
        t = pos - 1;     if (t >= 0 && t < LSEQ) xv1 = x[b * LSEQ + t];
        t = pos;         if (t >= 0 && t < LSEQ) xv2 = x[b * LSEQ + t];
    }
#pragma unroll
    for (int j = 0; j < 16; ++j) {
        int c = plu * 16 + j;
        float h = b0[c] + w0[c*3+0]*xv0 + w0[c*3+1]*xv1 + w0[c*3+2]*xv2;
        hbuf[c][pidx] = valid ? h : 0.f;
    }

    float skip[16];
#pragma unroll
    for (int j = 0; j < 16; ++j) skip[j] = 0.f;
    __syncthreads();

    // ---------------- 6 dilated gated residual blocks ----------------
    for (int lev = 0; lev < 6; ++lev) {
        const int d = 1 << lev;
        const float* wfT = wT + lev * 2048;            // [c][tap][co]
        const float* wgT = wT + 12288 + lev * 2048;
        const float* wsT = wT + 24576 + lev * 1024;    // [c][co]
        const float* wrT = wT + 30720 + lev * 1024;
        const int pm = (pidx >= d) ? (pidx - d) : 0;   // halo-clamped (garbage ok)

        float f[16], g[16];
#pragma unroll
        for (int j = 0; j < 16; ++j) {
            f[j] = bf[lev*32 + plu*16 + j];
            g[j] = bg[lev*32 + plu*16 + j];
        }
#pragma unroll 4
        for (int c = 0; c < 32; ++c) {
            const float hv  = hbuf[c][pidx];
            const float hmv = hbuf[c][pm];
            const float* w0p = wfT + c*64 + plu*16;        // tap0 (older)
            const float* w1p = w0p + 32;                   // tap1 (current)
            const float* u0p = wgT + c*64 + plu*16;
            const float* u1p = u0p + 32;
#pragma unroll
            for (int j = 0; j < 16; ++j) {
                f[j] = fmaf(w0p[j], hmv, f[j]);
                f[j] = fmaf(w1p[j], hv,  f[j]);
                g[j] = fmaf(u0p[j], hmv, g[j]);
                g[j] = fmaf(u1p[j], hv,  g[j]);
            }
        }
#pragma unroll
        for (int j = 0; j < 16; ++j)
            obuf[plu*16 + j][pidx] = fast_tanh(f[j]) * fast_sigmoid(g[j]);
        __syncthreads();   // out visible; also separates hbuf reads from h-update

        float s[16], r[16];
#pragma unroll
        for (int j = 0; j < 16; ++j) {
            s[j] = bs[lev*32 + plu*16 + j];
            r[j] = br[lev*32 + plu*16 + j];
        }
#pragma unroll 4
        for (int c = 0; c < 32; ++c) {
            const float ov = obuf[c][pidx];
            const float* sp = wsT + c*32 + plu*16;
            const float* rp = wrT + c*32 + plu*16;
#pragma unroll
            for (int j = 0; j < 16; ++j) {
                s[j] = fmaf(sp[j], ov, s[j]);
                r[j] = fmaf(rp[j], ov, r[j]);
            }
        }
#pragma unroll
        for (int j = 0; j < 16; ++j) {
            skip[j] += s[j];
            int row = plu*16 + j;
            float hn = hbuf[row][pidx] + r[j];
            hbuf[row][pidx] = valid ? hn : 0.f;     // keep pad zeros
        }
        __syncthreads();   // h update visible; obuf reads done before next overwrite
    }

    // ---------------- downsample conv (K=4, stride 4) ----------------
#pragma unroll
    for (int j = 0; j < 16; ++j) hbuf[plu*16 + j][pidx] = skip[j];  // sbuf
    __syncthreads();

    float* ybuf = &obuf[0][0];                 // [64][48] reuse
    {
        const int oc = tid >> 3;               // 0..63
        const int pg = tid & 7;
        float yv[6];
#pragma unroll
        for (int k = 0; k < 6; ++k) yv[k] = bd[oc];
#pragma unroll 4
        for (int c = 0; c < 32; ++c) {
            const float4 w4 = *(const float4*)&wd[(oc*32 + c) * 4];
#pragma unroll
            for (int k = 0; k < 6; ++k) {
                const int p = pg + 8*k;
                const float4 sv = *(const float4*)&hbuf[c][HALO + 4*p];
                yv[k] = fmaf(w4.x, sv.x, yv[k]);
                yv[k] = fmaf(w4.y, sv.y, yv[k]);
                yv[k] = fmaf(w4.z, sv.z, yv[k]);
                yv[k] = fmaf(w4.w, sv.w, yv[k]);
            }
        }
#pragma unroll
        for (int k = 0; k < 6; ++k) {
            const int p = pg + 8*k;
            ybuf[oc*48 + p] = (p0 + p < DL) ? yv[k] : 0.f;  // zero OOB tail
        }
    }
    __syncthreads();

    // ---------------- partial FC: o[b][j] += <y_tile, fcW[j] slice> ----------------
    const int wave = tid >> 6;
    const int lane = tid & 63;
    const float4* fcW4  = (const float4*)fcW;
    const float4* ybuf4 = (const float4*)ybuf;
    for (int j = wave; j < 64; j += 8) {
        float ax = 0.f, ay = 0.f, az = 0.f, aw = 0.f;
#pragma unroll 4
        for (int m = 0; m < 12; ++m) {
            const int k4 = lane + (m << 6);            // 0..767
            const int oc = (k4 * 5462) >> 16;          // k4/12
            const int pq = k4 - oc * 12;
            const bool inb = (p0 + 4*pq) < DL;
            const int idx4 = inb ? (j*360000 + oc*5625 + tile*12 + pq) : 0;
            const float4 w  = fcW4[idx4];
            const float4 yv = ybuf4[k4];               // 0 when !inb
            ax = fmaf(w.x, yv.x, ax);
            ay = fmaf(w.y, yv.y, ay);
            az = fmaf(w.z, yv.z, az);
            aw = fmaf(w.w, yv.w, aw);
        }
        float v = (ax + ay) + (az + aw);
#pragma unroll
        for (int off = 32; off > 0; off >>= 1) v += __shfl_down(v, off);
        if (lane == 0) atomicAdd(&oacc[b*64 + j], v);
    }
}

// mu / logvar / z from accumulated o
__global__ void fin_kernel(const float* __restrict__ oacc, const float* __restrict__ eps,
                           const float* __restrict__ fcb, float* __restrict__ out) {
    int t = threadIdx.x;                 // 256 = 8 batches * 32 latents
    int b = t >> 5, l = t & 31;
    float mu = oacc[b*64 + l]      + fcb[l];
    float lv = oacc[b*64 + 32 + l] + fcb[32 + l];
    float z  = fmaf(eps[t], expf(0.5f * lv), mu);
    out[t]       = mu;
    out[256 + t] = lv;
    out[512 + t] = z;
}

extern "C" void kernel_launch(void* const* d_in, const int* in_sizes, int n_in,
                              void* d_out, int out_size, void* d_ws, size_t ws_size,
                              hipStream_t stream) {
    const float* x   = (const float*)d_in[0];
    const float* eps = (const float*)d_in[1];
    const float* w0  = (const float*)d_in[2];
    const float* b0  = (const float*)d_in[3];
    const float* Wf  = (const float*)d_in[4];
    const float* bf  = (const float*)d_in[5];
    const float* Wg  = (const float*)d_in[6];
    const float* bg  = (const float*)d_in[7];
    const float* Ws  = (const float*)d_in[8];
    const float* bs  = (const float*)d_in[9];
    const float* Wr  = (const float*)d_in[10];
    const float* br  = (const float*)d_in[11];
    const float* wd  = (const float*)d_in[12];
    const float* bd  = (const float*)d_in[13];
    const float* fcW = (const float*)d_in[14];
    const float* fcb = (const float*)d_in[15];

    float* wsf  = (float*)d_ws;
    float* oacc = wsf;               // 512 floats
    const float* wT = wsf + 512;     // transposed weights

    prep_kernel<<<48, 256, 0, stream>>>(Wf, Wg, Ws, Wr, wsf);
    wavenet_kernel<<<NTILES * 8, TPB, 0, stream>>>(x, w0, b0, bf, bg, bs, br,
                                                   wd, bd, fcW, wT, oacc);
    fin_kernel<<<1, 256, 0, stream>>>(oacc, eps, fcb, (float*)d_out);
}

// Round 3
// 986.700 us; speedup vs baseline: 1.8494x; 1.8494x over previous
//
#include <hip/hip_runtime.h>
#include <hip/hip_bf16.h>
#include <math.h>

// ---------------- problem constants ----------------
#define TPB   512
#define NPOS  256        // positions per tile incl. 64 halo
#define HALO  64
#define PUSE  48         // useful downsampled positions per tile (192/4)
#define LSEQ  90000
#define DL    22500
#define NTILES 469       // ceil(22500/48)
#define HS    40         // LDS row stride (bf16 elems) for [pos][ch] tiles
#define SDS   136        // LDS row stride for skip-ds [p_ds][k=c*4+tap]

typedef __bf16 bf16x8 __attribute__((ext_vector_type(8)));
typedef __bf16 bf16x4 __attribute__((ext_vector_type(4)));
typedef float  f32x4  __attribute__((ext_vector_type(4)));

// ws layout: f32 oacc [0,512) ; then bf16 weights:
//   WFB 0      (6*32*64)   [lev][co][k=tap*32+cin]
//   WGB 12288
//   WSB 24576  (6*32*32)   [lev][co][cin]
//   WRB 30720
//   WDB 36864  (64*128)    [oc][k=cin*4+tap]
#define WFB 0
#define WGB 12288
#define WSB 24576
#define WRB 30720
#define WDB 36864

__device__ __forceinline__ f32x4 MFMA(bf16x8 a, bf16x8 b, f32x4 c) {
    return __builtin_amdgcn_mfma_f32_16x16x32_bf16(a, b, c, 0, 0, 0);
}
__device__ __forceinline__ float tanh_(float x) {
    float t = exp2f(x * 2.885390082f);                 // e^(2x)
    return 1.f - 2.f * __builtin_amdgcn_rcpf(t + 1.f); // ok at +/-inf
}
__device__ __forceinline__ float sig_(float x) {
    float e = exp2f(-x * 1.442695041f);                // e^(-x)
    return __builtin_amdgcn_rcpf(1.f + e);
}

// Cast/transpose weights to bf16 fragment-order + zero the o-accumulator.
__global__ void prep_kernel(const float* __restrict__ Wf, const float* __restrict__ Wg,
                            const float* __restrict__ Ws, const float* __restrict__ Wr,
                            const float* __restrict__ wd, float* __restrict__ ws) {
    int idx = blockIdx.x * 256 + threadIdx.x;   // grid 48*256 = 12288
    __bf16* wsb = (__bf16*)(ws + 512);
    if (idx < 512) ws[idx] = 0.f;
    if (idx < 12288) {
        // src flat ((lev*32+co)*32+cin)*2+tap -> [lev][co][tap*32+cin]
        int tap = idx & 1, cin = (idx >> 1) & 31, co = (idx >> 6) & 31, lev = idx >> 11;
        int dst = (lev * 32 + co) * 64 + tap * 32 + cin;
        wsb[WFB + dst] = (__bf16)Wf[idx];
        wsb[WGB + dst] = (__bf16)Wg[idx];
    }
    if (idx < 6144) {
        wsb[WSB + idx] = (__bf16)Ws[idx];
        wsb[WRB + idx] = (__bf16)Wr[idx];
    }
    if (idx < 8192) {
        wsb[WDB + idx] = (__bf16)wd[idx];
    }
}

__global__ __launch_bounds__(TPB, 4) void wavenet_kernel(
    const float* __restrict__ x,
    const float* __restrict__ w0, const float* __restrict__ b0,
    const float* __restrict__ bf, const float* __restrict__ bg,
    const float* __restrict__ bs, const float* __restrict__ br,
    const float* __restrict__ bd, const float* __restrict__ fcW,
    const __bf16* __restrict__ wsb,
    float* __restrict__ oacc)
{
    __shared__ __align__(16) unsigned char sm_h[NPOS * HS * 2];  // h (then skip-ds)
    __shared__ __align__(16) unsigned char sm_o[NPOS * HS * 2];  // out (then ybuf f32)
    __bf16* h16 = (__bf16*)sm_h;
    __bf16* o16 = (__bf16*)sm_o;
    __bf16* sd  = (__bf16*)sm_h;
    float*  ybuf = (float*)sm_o;

    const int tid  = threadIdx.x;
    const int b    = blockIdx.x & 7;
    const int tile = blockIdx.x >> 3;
    const int p0   = tile * PUSE;
    const int t0   = p0 * 4;

    // ---------------- h0 = causal conv K=3 (scalar fp32) ----------------
    {
        const int pidx = tid & 255, plane = tid >> 8;
        const int pos = t0 - HALO + pidx;
        const bool valid = (pos >= 0);
        float xv0 = 0.f, xv1 = 0.f, xv2 = 0.f;
        int t = pos - 2; if (t >= 0 && t < LSEQ) xv0 = x[b * LSEQ + t];
        t = pos - 1;     if (t >= 0 && t < LSEQ) xv1 = x[b * LSEQ + t];
        t = pos;         if (t >= 0 && t < LSEQ) xv2 = x[b * LSEQ + t];
        bf16x8 pk0, pk1;
#pragma unroll
        for (int j = 0; j < 16; ++j) {
            int c = plane * 16 + j;
            float h = b0[c] + w0[c*3+0]*xv0 + w0[c*3+1]*xv1 + w0[c*3+2]*xv2;
            __bf16 hb = valid ? (__bf16)h : (__bf16)0.f;
            if (j < 8) pk0[j] = hb; else pk1[j - 8] = hb;
        }
        *(bf16x8*)&h16[pidx * HS + plane * 16 + 0] = pk0;
        *(bf16x8*)&h16[pidx * HS + plane * 16 + 8] = pk1;
    }

    const int w  = tid >> 6;          // wave 0..7, owns cols 32w..32w+31
    const int l  = tid & 63;
    const int lm = l & 15;            // frag row/col
    const int lq = l >> 4;            // k-group / acc row group
    const int colbase = w * 32;

    float skip[2][2][4];
#pragma unroll
    for (int mt = 0; mt < 2; ++mt)
#pragma unroll
        for (int nt = 0; nt < 2; ++nt)
#pragma unroll
            for (int r = 0; r < 4; ++r) skip[mt][nt][r] = 0.f;

    // ---------------- 6 dilated gated residual blocks (MFMA) ----------------
    for (int lev = 0; lev < 6; ++lev) {
        const int d = 1 << lev;
        __syncthreads();   // B1: h from prev level / h0 visible

        // B-frags of h: [nt][ks]  ks0 = shifted (tap0), ks1 = current (tap1)
        bf16x8 bh[2][2];
#pragma unroll
        for (int nt = 0; nt < 2; ++nt) {
            int c0 = colbase + nt * 16 + lm;
            int cm = c0 - d; cm = cm < 0 ? 0 : cm;   // clamp (halo semantics)
            bh[nt][0] = *(bf16x8*)&h16[cm * HS + lq * 8];
            bh[nt][1] = *(bf16x8*)&h16[c0 * HS + lq * 8];
        }

        // f = Wf*h + bf ; g = Wg*h + bg
        f32x4 facc[2][2], gacc[2][2];
#pragma unroll
        for (int mt = 0; mt < 2; ++mt) {
#pragma unroll
            for (int r = 0; r < 4; ++r) {
                float bfv = bf[lev*32 + mt*16 + lq*4 + r];
                float bgv = bg[lev*32 + mt*16 + lq*4 + r];
#pragma unroll
                for (int nt = 0; nt < 2; ++nt) { facc[mt][nt][r] = bfv; gacc[mt][nt][r] = bgv; }
            }
        }
#pragma unroll
        for (int mt = 0; mt < 2; ++mt)
#pragma unroll
            for (int ks = 0; ks < 2; ++ks) {
                bf16x8 aF = *(bf16x8*)&wsb[WFB + (lev*32 + mt*16 + lm)*64 + ks*32 + lq*8];
#pragma unroll
                for (int nt = 0; nt < 2; ++nt) facc[mt][nt] = MFMA(aF, bh[nt][ks], facc[mt][nt]);
            }
#pragma unroll
        for (int mt = 0; mt < 2; ++mt)
#pragma unroll
            for (int ks = 0; ks < 2; ++ks) {
                bf16x8 aG = *(bf16x8*)&wsb[WGB + (lev*32 + mt*16 + lm)*64 + ks*32 + lq*8];
#pragma unroll
                for (int nt = 0; nt < 2; ++nt) gacc[mt][nt] = MFMA(aG, bh[nt][ks], gacc[mt][nt]);
            }

        __syncthreads();   // B2: all h reads done (updates follow)

        // out = tanh(f)*sigmoid(g) -> o16 [pos][ch] bf16
#pragma unroll
        for (int mt = 0; mt < 2; ++mt)
#pragma unroll
            for (int nt = 0; nt < 2; ++nt) {
                bf16x4 ob;
#pragma unroll
                for (int r = 0; r < 4; ++r)
                    ob[r] = (__bf16)(tanh_(facc[mt][nt][r]) * sig_(gacc[mt][nt][r]));
                int col = colbase + nt*16 + lm;
                *(bf16x4*)&o16[col * HS + mt*16 + lq*4] = ob;
            }

        // s = Ws*out + bs ; r = Wr*out + br   (same-wave LDS RAW -> lgkmcnt only)
        bf16x8 bo[2];
#pragma unroll
        for (int nt = 0; nt < 2; ++nt)
            bo[nt] = *(bf16x8*)&o16[(colbase + nt*16 + lm) * HS + lq*8];

        f32x4 sacc[2][2];
#pragma unroll
        for (int mt = 0; mt < 2; ++mt) {
#pragma unroll
            for (int r = 0; r < 4; ++r) {
                float bsv = bs[lev*32 + mt*16 + lq*4 + r];
#pragma unroll
                for (int nt = 0; nt < 2; ++nt) sacc[mt][nt][r] = bsv;
            }
        }
#pragma unroll
        for (int mt = 0; mt < 2; ++mt) {
            bf16x8 aS = *(bf16x8*)&wsb[WSB + (lev*32 + mt*16 + lm)*32 + lq*8];
#pragma unroll
            for (int nt = 0; nt < 2; ++nt) sacc[mt][nt] = MFMA(aS, bo[nt], sacc[mt][nt]);
        }
#pragma unroll
        for (int mt = 0; mt < 2; ++mt)
#pragma unroll
            for (int nt = 0; nt < 2; ++nt)
#pragma unroll
                for (int r = 0; r < 4; ++r) skip[mt][nt][r] += sacc[mt][nt][r];

        if (lev < 5) {
            f32x4 racc[2][2];
#pragma unroll
            for (int mt = 0; mt < 2; ++mt) {
#pragma unroll
                for (int r = 0; r < 4; ++r) {
                    float brv = br[lev*32 + mt*16 + lq*4 + r];
#pragma unroll
                    for (int nt = 0; nt < 2; ++nt) racc[mt][nt][r] = brv;
                }
            }
#pragma unroll
            for (int mt = 0; mt < 2; ++mt) {
                bf16x8 aR = *(bf16x8*)&wsb[WRB + (lev*32 + mt*16 + lm)*32 + lq*8];
#pragma unroll
                for (int nt = 0; nt < 2; ++nt) racc[mt][nt] = MFMA(aR, bo[nt], racc[mt][nt]);
            }
            // h += r (read-modify-write own cols)
#pragma unroll
            for (int mt = 0; mt < 2; ++mt)
#pragma unroll
                for (int nt = 0; nt < 2; ++nt) {
                    int col = colbase + nt*16 + lm;
                    int ad = col * HS + mt*16 + lq*4;
                    bf16x4 hold = *(bf16x4*)&h16[ad];
                    bf16x4 hnew;
#pragma unroll
                    for (int r = 0; r < 4; ++r)
                        hnew[r] = (__bf16)((float)hold[r] + racc[mt][nt][r]);
                    *(bf16x4*)&h16[ad] = hnew;
                }
            // tile 0: re-zero left-pad region (cols 0..63 == pos<0), wave-local
            if (tile == 0 && w < 2 && l < 32) {
                int col = w * 32 + l;
                bf16x8 z = {};
                *(bf16x8*)&h16[col * HS + 0]  = z;
                *(bf16x8*)&h16[col * HS + 8]  = z;
                *(bf16x8*)&h16[col * HS + 16] = z;
                *(bf16x8*)&h16[col * HS + 24] = z;
            }
        }
    }

    // ---------------- skip -> sd [p_ds][k=c*4+tap] bf16 (overlays h16) ----------------
    // All h16 reads completed at B2 of lev 5 (full barrier) -> safe to overwrite.
#pragma unroll
    for (int mt = 0; mt < 2; ++mt)
#pragma unroll
        for (int nt = 0; nt < 2; ++nt) {
            int col = colbase + nt*16 + lm;
            if (col >= HALO) {
                int p = col - HALO, pd = p >> 2, tap = p & 3;
#pragma unroll
                for (int r = 0; r < 4; ++r) {
                    int c = mt*16 + lq*4 + r;
                    sd[pd * SDS + c*4 + tap] = (__bf16)skip[mt][nt][r];
                }
            }
        }
    __syncthreads();   // B3: sd visible; o16 reads all done -> ybuf may overwrite

    // ---------------- downsample conv as MFMA: y[64][48] ----------------
#pragma unroll
    for (int pass = 0; pass < 2; ++pass) {
        int ct = w + 8 * pass;
        if (ct < 12) {
            int mt = ct / 3, nt = ct % 3;
            f32x4 yacc;
#pragma unroll
            for (int r = 0; r < 4; ++r) yacc[r] = bd[mt*16 + lq*4 + r];
#pragma unroll
            for (int ks = 0; ks < 4; ++ks) {
                bf16x8 aW = *(bf16x8*)&wsb[WDB + (mt*16 + lm)*128 + ks*32 + lq*8];
                bf16x8 bS = *(bf16x8*)&sd[(nt*16 + lm)*SDS + ks*32 + lq*8];
                yacc = MFMA(aW, bS, yacc);
            }
            int p = nt*16 + lm;
            bool inb = (p0 + p) < DL;
#pragma unroll
            for (int r = 0; r < 4; ++r)
                ybuf[(mt*16 + lq*4 + r)*48 + p] = inb ? yacc[r] : 0.f;
        }
    }
    __syncthreads();   // B4: ybuf visible

    // ---------------- partial FC: oacc[b][j] += <y_tile, fcW[j] slice> ----------------
    const float4* fcW4  = (const float4*)fcW;
    const float4* ybuf4 = (const float4*)ybuf;
    for (int j = w; j < 64; j += 8) {
        float ax = 0.f, ay = 0.f, az = 0.f, aw = 0.f;
#pragma unroll 4
        for (int m = 0; m < 12; ++m) {
            const int k4 = l + (m << 6);               // 0..767
            const int oc = (k4 * 5462) >> 16;          // k4/12
            const int pq = k4 - oc * 12;
            const bool inb = (p0 + 4*pq) < DL;
            const int idx4 = inb ? (j*360000 + oc*5625 + tile*12 + pq) : 0;
            const float4 wv = fcW4[idx4];
            const float4 yv = ybuf4[k4];               // 0 when !inb
            ax = fmaf(wv.x, yv.x, ax);
            ay = fmaf(wv.y, yv.y, ay);
            az = fmaf(wv.z, yv.z, az);
            aw = fmaf(wv.w, yv.w, aw);
        }
        float v = (ax + ay) + (az + aw);
#pragma unroll
        for (int off = 32; off > 0; off >>= 1) v += __shfl_down(v, off);
        if (l == 0) atomicAdd(&oacc[b*64 + j], v);
    }
}

// mu / logvar / z from accumulated o
__global__ void fin_kernel(const float* __restrict__ oacc, const float* __restrict__ eps,
                           const float* __restrict__ fcb, float* __restrict__ out) {
    int t = threadIdx.x;                 // 256 = 8 batches * 32 latents
    int b = t >> 5, lt = t & 31;
    float mu = oacc[b*64 + lt]      + fcb[lt];
    float lv = oacc[b*64 + 32 + lt] + fcb[32 + lt];
    float z  = fmaf(eps[t], expf(0.5f * lv), mu);
    out[t]       = mu;
    out[256 + t] = lv;
    out[512 + t] = z;
}

extern "C" void kernel_launch(void* const* d_in, const int* in_sizes, int n_in,
                              void* d_out, int out_size, void* d_ws, size_t ws_size,
                              hipStream_t stream) {
    const float* x   = (const float*)d_in[0];
    const float* eps = (const float*)d_in[1];
    const float* w0  = (const float*)d_in[2];
    const float* b0  = (const float*)d_in[3];
    const float* Wf  = (const float*)d_in[4];
    const float* bf  = (const float*)d_in[5];
    const float* Wg  = (const float*)d_in[6];
    const float* bg  = (const float*)d_in[7];
    const float* Ws  = (const float*)d_in[8];
    const float* bs  = (const float*)d_in[9];
    const float* Wr  = (const float*)d_in[10];
    const float* br  = (const float*)d_in[11];
    const float* wd  = (const float*)d_in[12];
    const float* bd  = (const float*)d_in[13];
    const float* fcW = (const float*)d_in[14];
    const float* fcb = (const float*)d_in[15];

    float* wsf  = (float*)d_ws;
    float* oacc = wsf;                          // 512 floats
    const __bf16* wsb = (const __bf16*)(wsf + 512);

    prep_kernel<<<48, 256, 0, stream>>>(Wf, Wg, Ws, Wr, wd, wsf);
    wavenet_kernel<<<NTILES * 8, TPB, 0, stream>>>(x, w0, b0, bf, bg, bs, br,
                                                   bd, fcW, wsb, oacc);
    fin_kernel<<<1, 256, 0, stream>>>(oacc, eps, fcb, (float*)d_out);
}